// Round 1
// baseline (5482.867 us; speedup 1.0000x reference)
//
#include <hip/hip_runtime.h>

// APPNP encoder: e_{k+1} = (1-alpha) * A @ e_k + ego, e_0 = 0, 3 layers.
// e_1 == ego, so only 2 SpMMs are needed:
//   e2 = ego + 0.9 * A @ ego
//   e3 = ego + 0.9 * A @ e2   -> output (user part then item part = full array)

#define USER_NUM 60000
#define ITEM_NUM 40000
#define N_NODES  100000
#define EMB      64
#define NNZ      3200000
#define ONE_MINUS_ALPHA 0.9f

// Copy concat(user_emb, item_emb) -> dst  (float4 vectorized)
__global__ __launch_bounds__(256) void init_ego(const float* __restrict__ user_emb,
                                                const float* __restrict__ item_emb,
                                                float* __restrict__ dst) {
    int idx = blockIdx.x * blockDim.x + threadIdx.x;   // float4 index
    const int total4 = N_NODES * EMB / 4;              // 1,600,000
    if (idx >= total4) return;
    const int user4 = USER_NUM * EMB / 4;              // 960,000
    float4 v;
    if (idx < user4) v = ((const float4*)user_emb)[idx];
    else             v = ((const float4*)item_emb)[idx - user4];
    ((float4*)dst)[idx] = v;
}

// SpMM gather from the split (user,item) ego source, accumulate into out.
// out must be pre-initialized with ego; we add 0.9*val*e[col] so out becomes e_next.
// 16 threads per nnz, each handles 4 consecutive emb components (float4).
__global__ __launch_bounds__(256) void spmm_ego(const int* __restrict__ rows,
                                                const int* __restrict__ cols,
                                                const float* __restrict__ vals,
                                                const float* __restrict__ user_emb,
                                                const float* __restrict__ item_emb,
                                                float* __restrict__ out) {
    unsigned tid = blockIdx.x * blockDim.x + threadIdx.x;
    if (tid >= (unsigned)NNZ * 16u) return;
    int i  = tid >> 4;
    int j4 = (tid & 15) << 2;
    int c = cols[i];
    int r = rows[i];
    float v = vals[i] * ONE_MINUS_ALPHA;
    const float* e = (c < USER_NUM) ? (user_emb + c * EMB)
                                    : (item_emb + (c - USER_NUM) * EMB);
    float4 ev = *(const float4*)(e + j4);
    float* o = out + r * EMB + j4;
    atomicAdd(o + 0, v * ev.x);
    atomicAdd(o + 1, v * ev.y);
    atomicAdd(o + 2, v * ev.z);
    atomicAdd(o + 3, v * ev.w);
}

// SpMM gather from a contiguous [N_NODES, EMB] source.
__global__ __launch_bounds__(256) void spmm_flat(const int* __restrict__ rows,
                                                 const int* __restrict__ cols,
                                                 const float* __restrict__ vals,
                                                 const float* __restrict__ e_in,
                                                 float* __restrict__ out) {
    unsigned tid = blockIdx.x * blockDim.x + threadIdx.x;
    if (tid >= (unsigned)NNZ * 16u) return;
    int i  = tid >> 4;
    int j4 = (tid & 15) << 2;
    int c = cols[i];
    int r = rows[i];
    float v = vals[i] * ONE_MINUS_ALPHA;
    float4 ev = *(const float4*)(e_in + c * EMB + j4);
    float* o = out + r * EMB + j4;
    atomicAdd(o + 0, v * ev.x);
    atomicAdd(o + 1, v * ev.y);
    atomicAdd(o + 2, v * ev.z);
    atomicAdd(o + 3, v * ev.w);
}

extern "C" void kernel_launch(void* const* d_in, const int* in_sizes, int n_in,
                              void* d_out, int out_size, void* d_ws, size_t ws_size,
                              hipStream_t stream) {
    const int*   rows     = (const int*)d_in[0];
    const int*   cols     = (const int*)d_in[1];
    const float* vals     = (const float*)d_in[2];
    const float* user_emb = (const float*)d_in[3];
    const float* item_emb = (const float*)d_in[4];
    float* out = (float*)d_out;

    float* e2 = (float*)d_ws;   // [N_NODES, EMB] = 25.6 MB

    const int copyBlocks = (N_NODES * EMB / 4 + 255) / 256;
    const int spmmThreads = NNZ * 16;
    const int spmmBlocks = (spmmThreads + 255) / 256;

    // e2 = ego
    init_ego<<<copyBlocks, 256, 0, stream>>>(user_emb, item_emb, e2);
    // e2 += 0.9 * A @ ego   (gather from split ego source)
    spmm_ego<<<spmmBlocks, 256, 0, stream>>>(rows, cols, vals, user_emb, item_emb, e2);
    // out = ego
    init_ego<<<copyBlocks, 256, 0, stream>>>(user_emb, item_emb, out);
    // out += 0.9 * A @ e2
    spmm_flat<<<spmmBlocks, 256, 0, stream>>>(rows, cols, vals, e2, out);
}

// Round 2
// 886.856 us; speedup vs baseline: 6.1824x; 6.1824x over previous
//
#include <hip/hip_runtime.h>

// APPNP encoder: e_{k+1} = 0.9 * A @ e_k + ego, e_0 = 0, 3 layers.
// e_1 == ego  =>  e2 = ego + 0.9*A@ego ; e3 = ego + 0.9*A@e2 (output).
//
// R2 strategy: build CSR on device (hist -> scan -> scatter), then PULL-based
// SpMM (deterministic register accumulation, one store per output element)
// to eliminate the 3.2 GB/dispatch atomic write-through seen in R1.

#define USER_NUM 60000
#define ITEM_NUM 40000
#define N_NODES  100000
#define EMB      64
#define NNZ      3200000
#define OMA      0.9f   // 1 - alpha

__device__ __forceinline__ const float* node_row(int n,
                                                 const float* __restrict__ ue,
                                                 const float* __restrict__ ie) {
    return (n < USER_NUM) ? (ue + (size_t)n * EMB)
                          : (ie + (size_t)(n - USER_NUM) * EMB);
}

// ---- CSR build ----------------------------------------------------------

__global__ __launch_bounds__(256) void hist_kernel(const int* __restrict__ rows,
                                                   int* __restrict__ hist) {
    int i = blockIdx.x * 256 + threadIdx.x;
    if (i < NNZ) atomicAdd(&hist[rows[i]], 1);
}

// Single-block exclusive scan over 100k bins; writes row_start and a cursor copy.
__global__ __launch_bounds__(256) void scan_kernel(const int* __restrict__ hist,
                                                   int* __restrict__ row_start,
                                                   int* __restrict__ cursor) {
    __shared__ int sums[256];
    const int per = (N_NODES + 255) / 256;  // 391
    int t = threadIdx.x;
    int b = t * per;
    int e = min(b + per, N_NODES);
    int s = 0;
    for (int i = b; i < e; ++i) s += hist[i];
    sums[t] = s;
    __syncthreads();
    if (t == 0) {
        int acc = 0;
        for (int i = 0; i < 256; ++i) { int v = sums[i]; sums[i] = acc; acc += v; }
    }
    __syncthreads();
    int acc = sums[t];
    for (int i = b; i < e; ++i) {
        row_start[i] = acc;
        cursor[i]    = acc;
        acc += hist[i];
    }
    if (t == 255) row_start[N_NODES] = acc;  // == NNZ
}

// Scatter edges into CSR order as packed (col, val*0.9).
__global__ __launch_bounds__(256) void scatter_kernel(const int* __restrict__ rows,
                                                      const int* __restrict__ cols,
                                                      const float* __restrict__ vals,
                                                      int* __restrict__ cursor,
                                                      int2* __restrict__ colval) {
    int i = blockIdx.x * 256 + threadIdx.x;
    if (i >= NNZ) return;
    int pos = atomicAdd(&cursor[rows[i]], 1);
    colval[pos] = make_int2(cols[i], __float_as_int(vals[i] * OMA));
}

// ---- Pull SpMM ----------------------------------------------------------
// 16 lanes per row; lane owns 4 consecutive emb floats (float4).
// Edges read 16-at-a-time coalesced, broadcast via shfl within the quarter-wave.

// Gather source = split ego (user_emb/item_emb); out = e2.
__global__ __launch_bounds__(256) void spmm_pull_ego(const int* __restrict__ row_start,
                                                     const int2* __restrict__ colval,
                                                     const float* __restrict__ ue,
                                                     const float* __restrict__ ie,
                                                     float* __restrict__ outb) {
    int tid = blockIdx.x * 256 + threadIdx.x;
    int r = tid >> 4;
    if (r >= N_NODES) return;
    int lane  = threadIdx.x & 15;
    int qbase = (threadIdx.x & 63) & ~15;  // quarter-wave base within the wave

    float4 acc = ((const float4*)node_row(r, ue, ie))[lane];  // acc = ego row chunk
    int s = row_start[r], e = row_start[r + 1];
    for (int k = s; k < e; k += 16) {
        int idx = k + lane;
        int2 cv = (idx < e) ? colval[idx] : make_int2(0, 0);  // pad: val=0
#pragma unroll
        for (int j = 0; j < 16; ++j) {
            int   cj = __shfl(cv.x, qbase + j, 64);
            float vj = __int_as_float(__shfl(cv.y, qbase + j, 64));
            float4 ev = ((const float4*)node_row(cj, ue, ie))[lane];
            acc.x += vj * ev.x; acc.y += vj * ev.y;
            acc.z += vj * ev.z; acc.w += vj * ev.w;
        }
    }
    ((float4*)(outb + (size_t)r * EMB))[lane] = acc;
}

// Gather source = flat e_in; acc init from split ego; out = e3 (d_out).
__global__ __launch_bounds__(256) void spmm_pull_flat(const int* __restrict__ row_start,
                                                      const int2* __restrict__ colval,
                                                      const float* __restrict__ e_in,
                                                      const float* __restrict__ ue,
                                                      const float* __restrict__ ie,
                                                      float* __restrict__ outb) {
    int tid = blockIdx.x * 256 + threadIdx.x;
    int r = tid >> 4;
    if (r >= N_NODES) return;
    int lane  = threadIdx.x & 15;
    int qbase = (threadIdx.x & 63) & ~15;

    float4 acc = ((const float4*)node_row(r, ue, ie))[lane];
    int s = row_start[r], e = row_start[r + 1];
    for (int k = s; k < e; k += 16) {
        int idx = k + lane;
        int2 cv = (idx < e) ? colval[idx] : make_int2(0, 0);
#pragma unroll
        for (int j = 0; j < 16; ++j) {
            int   cj = __shfl(cv.x, qbase + j, 64);
            float vj = __int_as_float(__shfl(cv.y, qbase + j, 64));
            float4 ev = ((const float4*)(e_in + (size_t)cj * EMB))[lane];
            acc.x += vj * ev.x; acc.y += vj * ev.y;
            acc.z += vj * ev.z; acc.w += vj * ev.w;
        }
    }
    ((float4*)(outb + (size_t)r * EMB))[lane] = acc;
}

// ---- launch -------------------------------------------------------------

extern "C" void kernel_launch(void* const* d_in, const int* in_sizes, int n_in,
                              void* d_out, int out_size, void* d_ws, size_t ws_size,
                              hipStream_t stream) {
    const int*   rows     = (const int*)d_in[0];
    const int*   cols     = (const int*)d_in[1];
    const float* vals     = (const float*)d_in[2];
    const float* user_emb = (const float*)d_in[3];
    const float* item_emb = (const float*)d_in[4];
    float* out = (float*)d_out;

    // workspace layout (bytes), 256-aligned blocks
    char* ws = (char*)d_ws;
    float* e2        = (float*)ws;                        // 25,600,000 B
    int2*  colval    = (int2*)(ws + 25600000);            // 25,600,000 B
    int*   hist      = (int*)(ws + 51200000);             //    400,000 B
    int*   row_start = (int*)(ws + 51600128);             //    400,004 B
    int*   cursor    = (int*)(ws + 52000256);             //    400,000 B
    // total ~52.4 MB

    hipMemsetAsync(hist, 0, N_NODES * sizeof(int), stream);

    const int edgeBlocks = (NNZ + 255) / 256;            // 12500
    hist_kernel<<<edgeBlocks, 256, 0, stream>>>(rows, hist);
    scan_kernel<<<1, 256, 0, stream>>>(hist, row_start, cursor);
    scatter_kernel<<<edgeBlocks, 256, 0, stream>>>(rows, cols, vals, cursor, colval);

    const int spmmBlocks = (N_NODES * 16 + 255) / 256;   // 6250
    spmm_pull_ego<<<spmmBlocks, 256, 0, stream>>>(row_start, colval, user_emb, item_emb, e2);
    spmm_pull_flat<<<spmmBlocks, 256, 0, stream>>>(row_start, colval, e2, user_emb, item_emb, out);
}